// Round 13
// baseline (408.456 us; speedup 1.0000x reference)
//
#include <hip/hip_runtime.h>

// HGNN layer, v25 — fp32. v24b (348.6µs best) with dispatch-count reduction
// 12 -> 8: init folded into linear; scan eliminated (atomic-cursor pair
// allocation — placement permutes, multiset identical, consumers are
// order-independent atomics); zero folded into sel (cached path; z aliases
// xT which is dead there); scale folded into edge (h1*s per read — same op
// sequence per term, bit-identical values). Count = v24b split-m float8
// (90µs, conflicts 55K). Sel = v13 bisection (proven). B=4, N=2304, C=64.

#define HB    4
#define HN    2304
#define HC    64
#define HK    11             // K_NEIGS + 1
#define HL    48
#define HW    22             // windows per dim
#define HE2   484            // 22*22 local edges
#define HE    (HN + HE2)
#define HRPB  4              // rows per block == waves per block
#define NSLOT 36             // keys per lane (2304/64)
#define NPAIRS (HB * HK * HN)   // sum of Dv == 11*N per batch, exact

__global__ void hg14_sentinel(float* out, int n) {
    int i = blockIdx.x * 256 + threadIdx.x;
    if (i < n) out[i] = 12345.0f;
}

// -------- linear h1 = x W^T + b, xsq, f32 transpose, + init (fused) -------
__global__ __launch_bounds__(64) void hg25_linear(const float* x, const float* W,
                                                  const float* bias, float* h1,
                                                  float* xsq, float* xT,
                                                  int* Dv, int* indeg, int* cursor,
                                                  float* bnsum, float* bnss) {
    int row = blockIdx.x;            // 0..B*N-1
    int t = threadIdx.x;
    if (t == 0) { Dv[row] = 0; indeg[row] = 0; }
    if (row == 0) {
        bnsum[t] = 0.f; bnss[t] = 0.f;
        if (t == 0) *cursor = 0;
    }
    __shared__ float xr[HC];
    float v = x[row * HC + t];
    xr[t] = v;
    __syncthreads();
    float sq = v * v;
    #pragma unroll
    for (int o = 32; o > 0; o >>= 1) sq += __shfl_xor(sq, o);
    if (t == 0) xsq[row] = sq;
    int b = row / HN, n = row % HN;
    xT[(b * HC + t) * HN + n] = v;
    float acc = bias[t];
    #pragma unroll 8
    for (int c = 0; c < HC; c++) acc += xr[c] * W[t * HC + c];
    h1[row * HC + t] = acc;
}

// ======== pop machinery (v12-proven): compile-time kk=11 in count only ====
__device__ __forceinline__ unsigned hg14_wave_min_u32(unsigned v) {
    #pragma unroll
    for (int o = 32; o > 0; o >>= 1) {
        unsigned ov = __shfl_xor(v, o);
        v = ov < v ? ov : v;
    }
    return v;
}

#define HG14_INS4(q0, q1, q2, q3, x)                                     \
    {                                                                    \
        unsigned long long x_ = (x), n_;                                 \
        n_ = q0 < x_ ? q0 : x_; x_ = q0 < x_ ? x_ : q0; q0 = n_;         \
        n_ = q1 < x_ ? q1 : x_; x_ = q1 < x_ ? x_ : q1; q1 = n_;         \
        n_ = q2 < x_ ? q2 : x_; x_ = q2 < x_ ? x_ : q2; q2 = n_;         \
        if (x_ < q3) q3 = x_;                                            \
    }

#define HG14_CE(u, v)                                                    \
    { unsigned long long t_ = u < v ? u : v; v = u < v ? v : u; u = t_; }

#define HG14_BUILD()                                                               \
    {                                                                              \
        unsigned long long a0 = CINF, a1 = CINF, a2 = CINF, a3 = CINF;             \
        unsigned long long b0 = CINF, b1 = CINF, b2 = CINF, b3 = CINF;             \
        _Pragma("unroll")                                                          \
        for (int s = 0; s < NSLOT / 2; s++) {                                      \
            unsigned long long pa = ((unsigned long long)key[s] << 12) |           \
                                    (unsigned)((s << 6) | lane);                   \
            unsigned long long pb = ((unsigned long long)key[s + 18] << 12) |      \
                                    (unsigned)(((s + 18) << 6) | lane);            \
            HG14_INS4(a0, a1, a2, a3, pa);                                         \
            HG14_INS4(b0, b1, b2, b3, pb);                                         \
        }                                                                          \
        c0 = a0 < b3 ? a0 : b3; c1 = a1 < b2 ? a1 : b2;                            \
        c2 = a2 < b1 ? a2 : b1; c3 = a3 < b0 ? a3 : b0;                            \
        HG14_CE(c0, c2); HG14_CE(c1, c3); HG14_CE(c0, c1); HG14_CE(c2, c3);        \
    }

#define HG14_EXTRACT(kk, EMIT)                                                     \
    {                                                                              \
        for (int j = 0; j < (kk); j++) {                                           \
            unsigned hk = (unsigned)(c0 >> 12);                                    \
            unsigned mk = hg14_wave_min_u32(hk);                                   \
            unsigned long long bal = __ballot(hk == mk);                           \
            bool iswin;                                                            \
            if (__popcll(bal) == 1) {                                              \
                iswin = (hk == mk);                                                \
            } else {                                                               \
                unsigned mc = (hk == mk) ? (unsigned)(c0 & 0xFFFu) : 0xFFFFFFFFu;  \
                unsigned mm = hg14_wave_min_u32(mc);                               \
                iswin = (mc == mm);                                                \
            }                                                                      \
            if (iswin) {                                                           \
                int bi = (int)(c0 & 0xFFFu);                                       \
                EMIT;                                                              \
                unsigned long long popped = c0;                                    \
                c0 = c1; c1 = c2; c2 = c3; c3 = CINF;                              \
                if (c0 == CINF) {                                                  \
                    _Pragma("unroll")                                              \
                    for (int s = 0; s < NSLOT; s++) {                              \
                        unsigned long long pk =                                    \
                            ((unsigned long long)key[s] << 12) |                   \
                            (unsigned)((s << 6) | lane);                           \
                        if (pk > popped) HG14_INS4(c0, c1, c2, c3, pk);            \
                    }                                                              \
                }                                                                  \
            }                                                                      \
        }                                                                          \
    }

// ======== bisection machinery (v13-proven): select path ===================
__device__ __forceinline__ void hg14_kth(const unsigned (&key)[NSLOT], int kk,
                                         unsigned& T, int& cntLess, int& take) {
    unsigned andv = 0xFFFFFFFFu, orv = 0u;
    #pragma unroll
    for (int s = 0; s < NSLOT; s++) { andv &= key[s]; orv |= key[s]; }
    #pragma unroll
    for (int o = 32; o > 0; o >>= 1) {
        andv &= (unsigned)__shfl_xor((int)andv, o);
        orv  |= (unsigned)__shfl_xor((int)orv, o);
    }
    unsigned diff = andv ^ orv;
    if (diff == 0u) { T = andv; cntLess = 0; take = kk; return; }
    int tstart = 31 - __builtin_clz(diff);
    unsigned lowmask = (tstart == 31) ? 0xFFFFFFFFu : ((1u << (tstart + 1)) - 1u);
    unsigned pref = andv & ~lowmask;
    int r = kk;
    for (int t = tstart; t >= 0; t--) {
        unsigned pt = pref >> t;
        int c = 0;
        #pragma unroll
        for (int s = 0; s < NSLOT; s++) c += ((key[s] >> t) == pt) ? 1 : 0;
        #pragma unroll
        for (int o = 32; o > 0; o >>= 1) c += __shfl_xor(c, o);
        if (r > c) { r -= c; pref |= (1u << t); }
    }
    T = pref; cntLess = kk - r; take = r;
}

__device__ __forceinline__ void hg14_scan64(int v, int lane, int& excl, int& total) {
    int inc = v;
    #pragma unroll
    for (int o = 1; o < 64; o <<= 1) {
        int u = __shfl_up(inc, o);
        if (lane >= o) inc += u;
    }
    excl = inc - v;
    total = __shfl(inc, 63);
}

// -------- kNN count v24: split-m float8 (two float4 chunks 1024 apart) ----
#define HG24_R4(qq, ss, ww)                                              \
    qq.x += (ss) * ww.x; qq.y += (ss) * ww.y;                            \
    qq.z += (ss) * ww.z; qq.w += (ss) * ww.w;

#define HG24_ST4(row, qq, sv, mm)                                              \
    *reinterpret_cast<float4*>(&d[row][(mm)]) =                                \
        make_float4(xs[row] + sv.x - 2.f * qq.x, xs[row] + sv.y - 2.f * qq.y,  \
                    xs[row] + sv.z - 2.f * qq.z, xs[row] + sv.w - 2.f * qq.w);

__global__ __launch_bounds__(256) void hg24_knn_count(const float* xT, const float* xsq,
                                                      int* Dv, unsigned int* kcache,
                                                      int storekeys) {
    __shared__ float d[HRPB][HN];                // 36 KB
    __shared__ __align__(16) float xrt[HC][HRPB];// [c][row] -> b128 uniform reads
    const int t = threadIdx.x;
    const int b = blockIdx.x / (HN / HRPB);
    const int n0 = (blockIdx.x % (HN / HRPB)) * HRPB;
    const int r = t >> 6;
    const int lane = t & 63;
    xrt[lane][r] = xT[(b * HC + lane) * HN + n0 + r];
    __syncthreads();
    float xs[HRPB];
    #pragma unroll
    for (int q = 0; q < HRPB; q++) xs[q] = xsq[b * HN + n0 + q];

    {
        const int m = 4 * t;                     // A in [0,1024), B in [1024,2048)
        float4 q0a = {0.f,0.f,0.f,0.f}, q0b = {0.f,0.f,0.f,0.f};
        float4 q1a = {0.f,0.f,0.f,0.f}, q1b = {0.f,0.f,0.f,0.f};
        float4 q2a = {0.f,0.f,0.f,0.f}, q2b = {0.f,0.f,0.f,0.f};
        float4 q3a = {0.f,0.f,0.f,0.f}, q3b = {0.f,0.f,0.f,0.f};
        #pragma unroll 8
        for (int c = 0; c < HC; c++) {
            float4 xq = *reinterpret_cast<const float4*>(&xrt[c][0]);
            const float* bp = &xT[(b * HC + c) * HN + m];
            float4 ua = *reinterpret_cast<const float4*>(bp);
            float4 ub = *reinterpret_cast<const float4*>(bp + 1024);
            HG24_R4(q0a, xq.x, ua); HG24_R4(q0b, xq.x, ub);
            HG24_R4(q1a, xq.y, ua); HG24_R4(q1b, xq.y, ub);
            HG24_R4(q2a, xq.z, ua); HG24_R4(q2b, xq.z, ub);
            HG24_R4(q3a, xq.w, ua); HG24_R4(q3b, xq.w, ub);
        }
        float4 s0 = *reinterpret_cast<const float4*>(&xsq[b * HN + m]);
        float4 s1 = *reinterpret_cast<const float4*>(&xsq[b * HN + m + 1024]);
        HG24_ST4(0, q0a, s0, m); HG24_ST4(0, q0b, s1, m + 1024);
        HG24_ST4(1, q1a, s0, m); HG24_ST4(1, q1b, s1, m + 1024);
        HG24_ST4(2, q2a, s0, m); HG24_ST4(2, q2b, s1, m + 1024);
        HG24_ST4(3, q3a, s0, m); HG24_ST4(3, q3b, s1, m + 1024);
    }
    if (t < 64) {                                // tail: m = 2048 + 4t .. 2303
        const int m = 2048 + 4 * t;
        float4 q0 = {0.f,0.f,0.f,0.f}, q1 = {0.f,0.f,0.f,0.f};
        float4 q2 = {0.f,0.f,0.f,0.f}, q3 = {0.f,0.f,0.f,0.f};
        #pragma unroll 8
        for (int c = 0; c < HC; c++) {
            float4 xq = *reinterpret_cast<const float4*>(&xrt[c][0]);
            float4 ua = *reinterpret_cast<const float4*>(&xT[(b * HC + c) * HN + m]);
            HG24_R4(q0, xq.x, ua); HG24_R4(q1, xq.y, ua);
            HG24_R4(q2, xq.z, ua); HG24_R4(q3, xq.w, ua);
        }
        float4 s0 = *reinterpret_cast<const float4*>(&xsq[b * HN + m]);
        HG24_ST4(0, q0, s0, m); HG24_ST4(1, q1, s0, m);
        HG24_ST4(2, q2, s0, m); HG24_ST4(3, q3, s0, m);
    }
    __syncthreads();

    const int p = n0 + r;
    const unsigned long long CINF = ~0ull;
    unsigned int key[NSLOT];
    unsigned long long c0, c1, c2, c3;
    const int rowbase = (b * HN + p) * NSLOT;
    #pragma unroll
    for (int s = 0; s < NSLOT; s++) {
        float f = d[r][(s << 6) | lane];
        unsigned int ub = __float_as_uint(f);
        unsigned int k = ub ^ (((unsigned int)(((int)ub) >> 31)) | 0x80000000u);
        key[s] = k;
        if (storekeys) kcache[(rowbase + s) * 64 + lane] = k;
    }
    HG14_BUILD();
    HG14_EXTRACT(HK, atomicAdd(&Dv[b * HN + bi], 1));
}

// -------- select body: threshold + parallel emission (v13-proven) ---------
__device__ __forceinline__ void hg14_select_emit(const unsigned (&key)[NSLOT],
                                                 int b, int p, int lane, int kk, int base,
                                                 int* indeg, unsigned int* pairs) {
    unsigned T; int cntLess, take;
    hg14_kth(key, kk, T, cntLess, take);
    int cl = 0;
    #pragma unroll
    for (int s = 0; s < NSLOT; s++) cl += (key[s] < T) ? 1 : 0;
    int off, tot;
    hg14_scan64(cl, lane, off, tot);
    int w = 0;
    #pragma unroll
    for (int s = 0; s < NSLOT; s++) {
        if (key[s] < T) {
            int m = (s << 6) | lane;
            atomicAdd(&indeg[b * HN + m], 1);
            pairs[base + off + w] =
                ((unsigned)b << 24) | ((unsigned)p << 12) | (unsigned)m;
            w++;
        }
    }
    int lastm = -1;
    for (int t2 = 0; t2 < take; t2++) {
        int mc = 0x7FFFFFFF;
        #pragma unroll
        for (int s = 0; s < NSLOT; s++) {
            int m = (s << 6) | lane;
            if (key[s] == T && m > lastm && m < mc) mc = m;
        }
        int mmin = mc;
        #pragma unroll
        for (int o = 32; o > 0; o >>= 1) {
            int ov = __shfl_xor(mmin, o);
            mmin = ov < mmin ? ov : mmin;
        }
        if (mc == mmin) {
            atomicAdd(&indeg[b * HN + mmin], 1);
            pairs[base + cntLess + t2] =
                ((unsigned)b << 24) | ((unsigned)p << 12) | (unsigned)mmin;
        }
        lastm = mmin;
    }
}

// -------- kNN select v25: cached keys + cursor alloc + z/h2 zeroing -------
__global__ __launch_bounds__(256) void hg25_sel(const unsigned int* kcache,
                                                const int* Dv, int* cursor,
                                                int* indeg, unsigned int* pairs,
                                                float* z, float* h2) {
    const int t = threadIdx.x;
    const int lane = t & 63;
    const int gw = blockIdx.x * HRPB + (t >> 6);   // global row 0..B*N-1
    const int b = gw / HN, p = gw % HN;
    // fused zeroing (was hg14_zero): h2 row + z kNN row. Safe: cached path
    // never reads xT (which z aliases); edge/gscatter run after this kernel.
    h2[gw * HC + lane] = 0.f;
    z[(b * HE + p) * HC + lane] = 0.f;
    unsigned int key[NSLOT];
    const int rowbase = gw * NSLOT;
    #pragma unroll
    for (int s = 0; s < NSLOT; s++) key[s] = kcache[(rowbase + s) * 64 + lane];
    int kk = max(Dv[gw], 1);
    int base = 0;
    if (lane == 0) base = atomicAdd(cursor, kk);
    base = __shfl(base, 0);
    hg14_select_emit(key, b, p, lane, kk, base, indeg, pairs);
}

// -------- kNN select, full recompute (fallback, no kcache ws) -------------
__global__ __launch_bounds__(256) void hg25_sel_full(const float* xT, const float* xsq,
                                                     const int* Dv, int* cursor,
                                                     int* indeg, unsigned int* pairs) {
    __shared__ float d[HRPB][HN];
    __shared__ float xr[HRPB][HC];
    const int t = threadIdx.x;
    const int b = blockIdx.x / (HN / HRPB);
    const int n0 = (blockIdx.x % (HN / HRPB)) * HRPB;
    const int r = t >> 6;
    const int lane = t & 63;
    xr[r][lane] = xT[(b * HC + lane) * HN + n0 + r];
    __syncthreads();
    float xs[HRPB];
    #pragma unroll
    for (int q = 0; q < HRPB; q++) xs[q] = xsq[b * HN + n0 + q];
    for (int m = t; m < HN; m += 256) {
        float dot0 = 0.f, dot1 = 0.f, dot2 = 0.f, dot3 = 0.f;
        #pragma unroll 8
        for (int c = 0; c < HC; c++) {
            float xv = xT[(b * HC + c) * HN + m];
            dot0 += xr[0][c] * xv;
            dot1 += xr[1][c] * xv;
            dot2 += xr[2][c] * xv;
            dot3 += xr[3][c] * xv;
        }
        float xsm = xsq[b * HN + m];
        d[0][m] = xs[0] + xsm - 2.f * dot0;
        d[1][m] = xs[1] + xsm - 2.f * dot1;
        d[2][m] = xs[2] + xsm - 2.f * dot2;
        d[3][m] = xs[3] + xsm - 2.f * dot3;
    }
    __syncthreads();
    const int p = n0 + r;
    unsigned int key[NSLOT];
    #pragma unroll
    for (int s = 0; s < NSLOT; s++) {
        float f = d[r][(s << 6) | lane];
        unsigned int ub = __float_as_uint(f);
        key[s] = ub ^ (((unsigned int)(((int)ub) >> 31)) | 0x80000000u);
    }
    const int gw = b * HN + p;
    int kk = max(Dv[gw], 1);
    int base = 0;
    if (lane == 0) base = atomicAdd(cursor, kk);
    base = __shfl(base, 0);
    hg14_select_emit(key, b, p, lane, kk, base, indeg, pairs);
}

// -------- zero z (kNN part) and h2 — FALLBACK PATH ONLY -------------------
__global__ void hg14_zero(float* z, float* h2) {
    int i = blockIdx.x * 256 + threadIdx.x;      // over B*N*C
    int b = i / (HN * HC), rem = i % (HN * HC);
    z[b * HE * HC + rem] = 0.f;
    h2[i] = 0.f;
}

__device__ __forceinline__ int hg14_lo(int rc) { return max(0, (rc - 3) / 2); }
__device__ __forceinline__ int hg14_hi(int rc) { return min(HW - 1, rc / 2); }

// per-node right-scale factor s(n) = rsqrt(max(indeg + cover, 1))
__device__ __forceinline__ float hg25_s(const int* indeg, int b, int n) {
    int r = n / HL, c = n % HL;
    int cover = max(0, hg14_hi(r) - hg14_lo(r) + 1) * max(0, hg14_hi(c) - hg14_lo(c) + 1);
    int dvn = max(indeg[b * HN + n] + cover, 1);
    return rsqrtf((float)dvn);
}

// -------- fused edge kernel: kNN scatter + window means (+ scale fused) ---
__global__ __launch_bounds__(256) void hg25_edge(const unsigned int* pairs, const int* Dv,
                                                 const int* indeg, const float* y, float* z) {
    int wv = (blockIdx.x * 256 + threadIdx.x) >> 6;
    int lane = threadIdx.x & 63;
    if (wv < NPAIRS) {
        unsigned int pk = pairs[wv];
        int b = pk >> 24;
        if (b >= HB) return;                     // defensive (poison)
        int p = (pk >> 12) & 0xFFF, m = pk & 0xFFF;
        float invde = 1.f / (float)max(Dv[b * HN + p], 1);
        float sc = hg25_s(indeg, b, m);
        atomicAdd(&z[(b * HE + p) * HC + lane],
                  (y[(b * HN + m) * HC + lane] * sc) * invde);
    } else {
        int w2 = wv - NPAIRS;
        if (w2 >= HB * HE2) return;
        int b = w2 / HE2, w = w2 % HE2;
        int wr = w / HW, wc = w % HW;
        float acc = 0.f;
        #pragma unroll
        for (int i = 0; i < 5; i++)
            #pragma unroll
            for (int j = 0; j < 5; j++) {
                int n2 = (wr * 2 + i) * HL + wc * 2 + j;
                acc += y[(b * HN + n2) * HC + lane] * hg25_s(indeg, b, n2);
            }
        z[(b * HE + HN + w) * HC + lane] = acc * (1.f / 25.f);
    }
}

// -------- h2[m] += z[p] over the pair list (atomic) -----------------------
__global__ __launch_bounds__(256) void hg14_gscatter(const unsigned int* pairs,
                                                     const float* z, float* h2) {
    int idx = (blockIdx.x * 256 + threadIdx.x) >> 6;
    int lane = threadIdx.x & 63;
    if (idx >= NPAIRS) return;
    unsigned int pk = pairs[idx];
    int b = pk >> 24;
    if (b >= HB) return;                         // defensive (poison)
    int p = (pk >> 12) & 0xFFF, m = pk & 0xFFF;
    atomicAdd(&h2[(b * HN + m) * HC + lane], z[(b * HE + p) * HC + lane]);
}

// -------- add window contributions + final Dv^-1/2 scale ------------------
__global__ __launch_bounds__(256) void hg14_gfinish(const float* z, const int* indeg, float* h2) {
    int wave = (blockIdx.x * 256 + threadIdx.x) >> 6;  // one wave per (b, node)
    int lane = threadIdx.x & 63;
    int b = wave / HN, n = wave % HN;
    int g = b * HN + n;
    float acc = h2[g * HC + lane];
    int r = n / HL, c = n % HL;
    int rlo = hg14_lo(r), rhi = hg14_hi(r), clo = hg14_lo(c), chi = hg14_hi(c);
    for (int wr = rlo; wr <= rhi; wr++)
        for (int wc = clo; wc <= chi; wc++)
            acc += z[(b * HE + HN + wr * HW + wc) * HC + lane];
    int dvn = max(indeg[g] + max(0, rhi - rlo + 1) * max(0, chi - clo + 1), 1);
    h2[g * HC + lane] = acc * rsqrtf((float)dvn);
}

// -------- BN stats --------------------------------------------------------
__global__ __launch_bounds__(256) void hg14_bnstats(const float* h2, float* bnsum, float* bnss) {
    int t = threadIdx.x;
    int c = t & 63, rg = t >> 6;
    int row0 = blockIdx.x * 36;      // 256 blocks * 36 rows = 9216
    float s = 0.f, ss = 0.f;
    for (int r = rg; r < 36; r += 4) {
        float v = h2[(row0 + r) * HC + c];
        s += v; ss += v * v;
    }
    __shared__ float ls[256], lss[256];
    ls[t] = s; lss[t] = ss;
    __syncthreads();
    if (t < 64) {
        s  = ls[t]  + ls[t + 64]  + ls[t + 128]  + ls[t + 192];
        ss = lss[t] + lss[t + 64] + lss[t + 128] + lss[t + 192];
        atomicAdd(&bnsum[t], s);
        atomicAdd(&bnss[t], ss);
    }
}

// -------- BN + ReLU + residual --------------------------------------------
__global__ __launch_bounds__(256) void hg14_final(const float* h2, const float* x,
                                                  const float* gamma, const float* beta,
                                                  const float* bnsum, const float* bnss,
                                                  float* out) {
    int i = blockIdx.x * 256 + threadIdx.x;
    int c = i & 63;
    const float M = (float)(HB * HN);
    float mean = bnsum[c] / M;
    float var  = bnss[c] / M - mean * mean;
    float inv  = rsqrtf(var + 1e-5f);
    float h = gamma[c] * (h2[i] - mean) * inv + beta[c];
    out[i] = fmaxf(h, 0.f) + x[i];
}

extern "C" void kernel_launch(void* const* d_in, const int* in_sizes, int n_in,
                              void* d_out, int out_size, void* d_ws, size_t ws_size,
                              hipStream_t stream) {
    const float* x     = (const float*)d_in[0];
    const float* W     = (const float*)d_in[1];
    const float* bias  = (const float*)d_in[2];
    const float* gamma = (const float*)d_in[3];
    const float* beta  = (const float*)d_in[4];
    float* out = (float*)d_out;
    (void)in_sizes; (void)n_in;

    char* ws = (char*)d_ws;
    size_t off = 0;
    float*        xsq     = (float*)(ws + off);        off += (size_t)HB * HN * 4;
    float*        h1      = (float*)(ws + off);        off += (size_t)HB * HN * HC * 4;
    float*        h2      = (float*)(ws + off);        off += (size_t)HB * HN * HC * 4;
    int*          Dv      = (int*)(ws + off);          off += (size_t)HB * HN * 4;
    int*          indeg   = (int*)(ws + off);          off += (size_t)HB * HN * 4;
    int*          cursor  = (int*)(ws + off);          off += 256;
    unsigned int* pairs   = (unsigned int*)(ws + off); off += (size_t)NPAIRS * 4;
    float*        bnsum   = (float*)(ws + off);        off += 256;
    float*        bnss    = (float*)(ws + off);        off += 256;
    float*        xT      = (float*)(ws + off);        // z aliases xT (dead after kNN)
    float*        z       = (float*)(ws + off);
    off += (size_t)HB * HE * HC * 4;   // max(xT, z) = z
    size_t base_need = off;
    unsigned int* kcache  = (unsigned int*)(ws + off);
    size_t cache_need = off + (size_t)HB * HN * NSLOT * 64 * 4;   // +84.9 MB

    if (ws_size < base_need) {
        hg14_sentinel<<<(out_size + 255) / 256, 256, 0, stream>>>(out, out_size);
        return;
    }
    const int use_cache = (ws_size >= cache_need) ? 1 : 0;

    const int EDGE_WAVES = NPAIRS + HB * HE2;    // 103312, divisible by 4

    hg25_linear<<<HB * HN, 64, 0, stream>>>(x, W, bias, h1, xsq, xT,
                                            Dv, indeg, cursor, bnsum, bnss);
    hg24_knn_count<<<HB * (HN / HRPB), 256, 0, stream>>>(xT, xsq, Dv, kcache, use_cache);
    if (use_cache) {
        hg25_sel<<<HB * (HN / HRPB), 256, 0, stream>>>(kcache, Dv, cursor, indeg,
                                                       pairs, z, h2);
    } else {
        hg25_sel_full<<<HB * (HN / HRPB), 256, 0, stream>>>(xT, xsq, Dv, cursor,
                                                            indeg, pairs);
        hg14_zero<<<(HB * HN * HC) / 256, 256, 0, stream>>>(z, h2);
    }
    hg25_edge<<<EDGE_WAVES / 4, 256, 0, stream>>>(pairs, Dv, indeg, h1, z);
    hg14_gscatter<<<(NPAIRS * 64) / 256, 256, 0, stream>>>(pairs, z, h2);
    hg14_gfinish<<<(HB * HN) / 4, 256, 0, stream>>>(z, indeg, h2);
    hg14_bnstats<<<256, 256, 0, stream>>>(h2, bnsum, bnss);
    hg14_final<<<(HB * HN * HC) / 256, 256, 0, stream>>>(h2, x, gamma, beta, bnsum, bnss, out);
}

// Round 14
// 347.060 us; speedup vs baseline: 1.1769x; 1.1769x over previous
//
#include <hip/hip_runtime.h>

// HGNN layer, v26 — fp32. v25's GOOD fusions kept (init->linear, scale->edge,
// zero->sel: measured -39µs dispatch savings), v25's BAD cursor allocator
// reverted (9216 same-address atomicAdds serialized: sel 48->147µs, VGPR
// spill to 32). Placement restored to the proven hg15_scan + offs[] path.
// Count = v24b split-m float8 (90µs). 9 dispatches. B=4, N=2304, C=64.

#define HB    4
#define HN    2304
#define HC    64
#define HK    11             // K_NEIGS + 1
#define HL    48
#define HW    22             // windows per dim
#define HE2   484            // 22*22 local edges
#define HE    (HN + HE2)
#define HRPB  4              // rows per block == waves per block
#define NSLOT 36             // keys per lane (2304/64)
#define NPAIRS (HB * HK * HN)   // sum of Dv == 11*N per batch, exact

__global__ void hg14_sentinel(float* out, int n) {
    int i = blockIdx.x * 256 + threadIdx.x;
    if (i < n) out[i] = 12345.0f;
}

// -------- linear h1 = x W^T + b, xsq, f32 transpose, + init (fused) -------
__global__ __launch_bounds__(64) void hg25_linear(const float* x, const float* W,
                                                  const float* bias, float* h1,
                                                  float* xsq, float* xT,
                                                  int* Dv, int* indeg,
                                                  float* bnsum, float* bnss) {
    int row = blockIdx.x;            // 0..B*N-1
    int t = threadIdx.x;
    if (t == 0) { Dv[row] = 0; indeg[row] = 0; }
    if (row == 0) { bnsum[t] = 0.f; bnss[t] = 0.f; }
    __shared__ float xr[HC];
    float v = x[row * HC + t];
    xr[t] = v;
    __syncthreads();
    float sq = v * v;
    #pragma unroll
    for (int o = 32; o > 0; o >>= 1) sq += __shfl_xor(sq, o);
    if (t == 0) xsq[row] = sq;
    int b = row / HN, n = row % HN;
    xT[(b * HC + t) * HN + n] = v;
    float acc = bias[t];
    #pragma unroll 8
    for (int c = 0; c < HC; c++) acc += xr[c] * W[t * HC + c];
    h1[row * HC + t] = acc;
}

// ======== pop machinery (v12-proven): compile-time kk=11 in count only ====
__device__ __forceinline__ unsigned hg14_wave_min_u32(unsigned v) {
    #pragma unroll
    for (int o = 32; o > 0; o >>= 1) {
        unsigned ov = __shfl_xor(v, o);
        v = ov < v ? ov : v;
    }
    return v;
}

#define HG14_INS4(q0, q1, q2, q3, x)                                     \
    {                                                                    \
        unsigned long long x_ = (x), n_;                                 \
        n_ = q0 < x_ ? q0 : x_; x_ = q0 < x_ ? x_ : q0; q0 = n_;         \
        n_ = q1 < x_ ? q1 : x_; x_ = q1 < x_ ? x_ : q1; q1 = n_;         \
        n_ = q2 < x_ ? q2 : x_; x_ = q2 < x_ ? x_ : q2; q2 = n_;         \
        if (x_ < q3) q3 = x_;                                            \
    }

#define HG14_CE(u, v)                                                    \
    { unsigned long long t_ = u < v ? u : v; v = u < v ? v : u; u = t_; }

#define HG14_BUILD()                                                               \
    {                                                                              \
        unsigned long long a0 = CINF, a1 = CINF, a2 = CINF, a3 = CINF;             \
        unsigned long long b0 = CINF, b1 = CINF, b2 = CINF, b3 = CINF;             \
        _Pragma("unroll")                                                          \
        for (int s = 0; s < NSLOT / 2; s++) {                                      \
            unsigned long long pa = ((unsigned long long)key[s] << 12) |           \
                                    (unsigned)((s << 6) | lane);                   \
            unsigned long long pb = ((unsigned long long)key[s + 18] << 12) |      \
                                    (unsigned)(((s + 18) << 6) | lane);            \
            HG14_INS4(a0, a1, a2, a3, pa);                                         \
            HG14_INS4(b0, b1, b2, b3, pb);                                         \
        }                                                                          \
        c0 = a0 < b3 ? a0 : b3; c1 = a1 < b2 ? a1 : b2;                            \
        c2 = a2 < b1 ? a2 : b1; c3 = a3 < b0 ? a3 : b0;                            \
        HG14_CE(c0, c2); HG14_CE(c1, c3); HG14_CE(c0, c1); HG14_CE(c2, c3);        \
    }

#define HG14_EXTRACT(kk, EMIT)                                                     \
    {                                                                              \
        for (int j = 0; j < (kk); j++) {                                           \
            unsigned hk = (unsigned)(c0 >> 12);                                    \
            unsigned mk = hg14_wave_min_u32(hk);                                   \
            unsigned long long bal = __ballot(hk == mk);                           \
            bool iswin;                                                            \
            if (__popcll(bal) == 1) {                                              \
                iswin = (hk == mk);                                                \
            } else {                                                               \
                unsigned mc = (hk == mk) ? (unsigned)(c0 & 0xFFFu) : 0xFFFFFFFFu;  \
                unsigned mm = hg14_wave_min_u32(mc);                               \
                iswin = (mc == mm);                                                \
            }                                                                      \
            if (iswin) {                                                           \
                int bi = (int)(c0 & 0xFFFu);                                       \
                EMIT;                                                              \
                unsigned long long popped = c0;                                    \
                c0 = c1; c1 = c2; c2 = c3; c3 = CINF;                              \
                if (c0 == CINF) {                                                  \
                    _Pragma("unroll")                                              \
                    for (int s = 0; s < NSLOT; s++) {                              \
                        unsigned long long pk =                                    \
                            ((unsigned long long)key[s] << 12) |                   \
                            (unsigned)((s << 6) | lane);                           \
                        if (pk > popped) HG14_INS4(c0, c1, c2, c3, pk);            \
                    }                                                              \
                }                                                                  \
            }                                                                      \
        }                                                                          \
    }

// ======== bisection machinery (v13-proven): select path ===================
__device__ __forceinline__ void hg14_kth(const unsigned (&key)[NSLOT], int kk,
                                         unsigned& T, int& cntLess, int& take) {
    unsigned andv = 0xFFFFFFFFu, orv = 0u;
    #pragma unroll
    for (int s = 0; s < NSLOT; s++) { andv &= key[s]; orv |= key[s]; }
    #pragma unroll
    for (int o = 32; o > 0; o >>= 1) {
        andv &= (unsigned)__shfl_xor((int)andv, o);
        orv  |= (unsigned)__shfl_xor((int)orv, o);
    }
    unsigned diff = andv ^ orv;
    if (diff == 0u) { T = andv; cntLess = 0; take = kk; return; }
    int tstart = 31 - __builtin_clz(diff);
    unsigned lowmask = (tstart == 31) ? 0xFFFFFFFFu : ((1u << (tstart + 1)) - 1u);
    unsigned pref = andv & ~lowmask;
    int r = kk;
    for (int t = tstart; t >= 0; t--) {
        unsigned pt = pref >> t;
        int c = 0;
        #pragma unroll
        for (int s = 0; s < NSLOT; s++) c += ((key[s] >> t) == pt) ? 1 : 0;
        #pragma unroll
        for (int o = 32; o > 0; o >>= 1) c += __shfl_xor(c, o);
        if (r > c) { r -= c; pref |= (1u << t); }
    }
    T = pref; cntLess = kk - r; take = r;
}

__device__ __forceinline__ void hg14_scan64(int v, int lane, int& excl, int& total) {
    int inc = v;
    #pragma unroll
    for (int o = 1; o < 64; o <<= 1) {
        int u = __shfl_up(inc, o);
        if (lane >= o) inc += u;
    }
    excl = inc - v;
    total = __shfl(inc, 63);
}

// -------- kNN count v24: split-m float8 (two float4 chunks 1024 apart) ----
#define HG24_R4(qq, ss, ww)                                              \
    qq.x += (ss) * ww.x; qq.y += (ss) * ww.y;                            \
    qq.z += (ss) * ww.z; qq.w += (ss) * ww.w;

#define HG24_ST4(row, qq, sv, mm)                                              \
    *reinterpret_cast<float4*>(&d[row][(mm)]) =                                \
        make_float4(xs[row] + sv.x - 2.f * qq.x, xs[row] + sv.y - 2.f * qq.y,  \
                    xs[row] + sv.z - 2.f * qq.z, xs[row] + sv.w - 2.f * qq.w);

__global__ __launch_bounds__(256) void hg24_knn_count(const float* xT, const float* xsq,
                                                      int* Dv, unsigned int* kcache,
                                                      int storekeys) {
    __shared__ float d[HRPB][HN];                // 36 KB
    __shared__ __align__(16) float xrt[HC][HRPB];// [c][row] -> b128 uniform reads
    const int t = threadIdx.x;
    const int b = blockIdx.x / (HN / HRPB);
    const int n0 = (blockIdx.x % (HN / HRPB)) * HRPB;
    const int r = t >> 6;
    const int lane = t & 63;
    xrt[lane][r] = xT[(b * HC + lane) * HN + n0 + r];
    __syncthreads();
    float xs[HRPB];
    #pragma unroll
    for (int q = 0; q < HRPB; q++) xs[q] = xsq[b * HN + n0 + q];

    {
        const int m = 4 * t;                     // A in [0,1024), B in [1024,2048)
        float4 q0a = {0.f,0.f,0.f,0.f}, q0b = {0.f,0.f,0.f,0.f};
        float4 q1a = {0.f,0.f,0.f,0.f}, q1b = {0.f,0.f,0.f,0.f};
        float4 q2a = {0.f,0.f,0.f,0.f}, q2b = {0.f,0.f,0.f,0.f};
        float4 q3a = {0.f,0.f,0.f,0.f}, q3b = {0.f,0.f,0.f,0.f};
        #pragma unroll 8
        for (int c = 0; c < HC; c++) {
            float4 xq = *reinterpret_cast<const float4*>(&xrt[c][0]);
            const float* bp = &xT[(b * HC + c) * HN + m];
            float4 ua = *reinterpret_cast<const float4*>(bp);
            float4 ub = *reinterpret_cast<const float4*>(bp + 1024);
            HG24_R4(q0a, xq.x, ua); HG24_R4(q0b, xq.x, ub);
            HG24_R4(q1a, xq.y, ua); HG24_R4(q1b, xq.y, ub);
            HG24_R4(q2a, xq.z, ua); HG24_R4(q2b, xq.z, ub);
            HG24_R4(q3a, xq.w, ua); HG24_R4(q3b, xq.w, ub);
        }
        float4 s0 = *reinterpret_cast<const float4*>(&xsq[b * HN + m]);
        float4 s1 = *reinterpret_cast<const float4*>(&xsq[b * HN + m + 1024]);
        HG24_ST4(0, q0a, s0, m); HG24_ST4(0, q0b, s1, m + 1024);
        HG24_ST4(1, q1a, s0, m); HG24_ST4(1, q1b, s1, m + 1024);
        HG24_ST4(2, q2a, s0, m); HG24_ST4(2, q2b, s1, m + 1024);
        HG24_ST4(3, q3a, s0, m); HG24_ST4(3, q3b, s1, m + 1024);
    }
    if (t < 64) {                                // tail: m = 2048 + 4t .. 2303
        const int m = 2048 + 4 * t;
        float4 q0 = {0.f,0.f,0.f,0.f}, q1 = {0.f,0.f,0.f,0.f};
        float4 q2 = {0.f,0.f,0.f,0.f}, q3 = {0.f,0.f,0.f,0.f};
        #pragma unroll 8
        for (int c = 0; c < HC; c++) {
            float4 xq = *reinterpret_cast<const float4*>(&xrt[c][0]);
            float4 ua = *reinterpret_cast<const float4*>(&xT[(b * HC + c) * HN + m]);
            HG24_R4(q0, xq.x, ua); HG24_R4(q1, xq.y, ua);
            HG24_R4(q2, xq.z, ua); HG24_R4(q3, xq.w, ua);
        }
        float4 s0 = *reinterpret_cast<const float4*>(&xsq[b * HN + m]);
        HG24_ST4(0, q0, s0, m); HG24_ST4(1, q1, s0, m);
        HG24_ST4(2, q2, s0, m); HG24_ST4(3, q3, s0, m);
    }
    __syncthreads();

    const int p = n0 + r;
    const unsigned long long CINF = ~0ull;
    unsigned int key[NSLOT];
    unsigned long long c0, c1, c2, c3;
    const int rowbase = (b * HN + p) * NSLOT;
    #pragma unroll
    for (int s = 0; s < NSLOT; s++) {
        float f = d[r][(s << 6) | lane];
        unsigned int ub = __float_as_uint(f);
        unsigned int k = ub ^ (((unsigned int)(((int)ub) >> 31)) | 0x80000000u);
        key[s] = k;
        if (storekeys) kcache[(rowbase + s) * 64 + lane] = k;
    }
    HG14_BUILD();
    HG14_EXTRACT(HK, atomicAdd(&Dv[b * HN + bi], 1));
}

// -------- exclusive scan of Dv (9216 = 256*36) into offs, wave-parallel ---
__global__ __launch_bounds__(256) void hg15_scan(const int* Dv, int* offs) {
    __shared__ int wsum[4];
    int t = threadIdx.x;
    int lane = t & 63, w = t >> 6;
    int base = t * 36;
    int s = 0;
    for (int i = 0; i < 36; i++) s += max(Dv[base + i], 1);
    int inc = s;
    #pragma unroll
    for (int o = 1; o < 64; o <<= 1) {
        int u = __shfl_up(inc, o);
        if (lane >= o) inc += u;
    }
    if (lane == 63) wsum[w] = inc;
    __syncthreads();
    int woff = 0;
    for (int i = 0; i < w; i++) woff += wsum[i];
    int acc = woff + inc - s;                    // exclusive prefix for this thread
    for (int i = 0; i < 36; i++) { offs[base + i] = acc; acc += max(Dv[base + i], 1); }
}

// -------- select body: threshold + parallel emission (v13-proven) ---------
__device__ __forceinline__ void hg14_select_emit(const unsigned (&key)[NSLOT],
                                                 int b, int p, int lane, int kk, int base,
                                                 int* indeg, unsigned int* pairs) {
    unsigned T; int cntLess, take;
    hg14_kth(key, kk, T, cntLess, take);
    int cl = 0;
    #pragma unroll
    for (int s = 0; s < NSLOT; s++) cl += (key[s] < T) ? 1 : 0;
    int off, tot;
    hg14_scan64(cl, lane, off, tot);
    int w = 0;
    #pragma unroll
    for (int s = 0; s < NSLOT; s++) {
        if (key[s] < T) {
            int m = (s << 6) | lane;
            atomicAdd(&indeg[b * HN + m], 1);
            pairs[base + off + w] =
                ((unsigned)b << 24) | ((unsigned)p << 12) | (unsigned)m;
            w++;
        }
    }
    int lastm = -1;
    for (int t2 = 0; t2 < take; t2++) {
        int mc = 0x7FFFFFFF;
        #pragma unroll
        for (int s = 0; s < NSLOT; s++) {
            int m = (s << 6) | lane;
            if (key[s] == T && m > lastm && m < mc) mc = m;
        }
        int mmin = mc;
        #pragma unroll
        for (int o = 32; o > 0; o >>= 1) {
            int ov = __shfl_xor(mmin, o);
            mmin = ov < mmin ? ov : mmin;
        }
        if (mc == mmin) {
            atomicAdd(&indeg[b * HN + mmin], 1);
            pairs[base + cntLess + t2] =
                ((unsigned)b << 24) | ((unsigned)p << 12) | (unsigned)mmin;
        }
        lastm = mmin;
    }
}

// -------- kNN select v26: cached keys + offs placement + z/h2 zeroing -----
__global__ __launch_bounds__(256) void hg26_sel(const unsigned int* kcache,
                                                const int* Dv, const int* offs,
                                                int* indeg, unsigned int* pairs,
                                                float* z, float* h2) {
    const int t = threadIdx.x;
    const int lane = t & 63;
    const int gw = blockIdx.x * HRPB + (t >> 6);   // global row 0..B*N-1
    const int b = gw / HN, p = gw % HN;
    // fused zeroing (was hg14_zero): h2 row + z kNN row. Safe: cached path
    // never reads xT (which z aliases); edge/gscatter run after this kernel.
    h2[gw * HC + lane] = 0.f;
    z[(b * HE + p) * HC + lane] = 0.f;
    unsigned int key[NSLOT];
    const int rowbase = gw * NSLOT;
    #pragma unroll
    for (int s = 0; s < NSLOT; s++) key[s] = kcache[(rowbase + s) * 64 + lane];
    hg14_select_emit(key, b, p, lane, max(Dv[gw], 1), offs[gw], indeg, pairs);
}

// -------- kNN select, full recompute (fallback, no kcache ws) -------------
__global__ __launch_bounds__(256) void hg14_knn_sel_full(const float* xT, const float* xsq,
                                                         const int* Dv, const int* offs,
                                                         int* indeg, unsigned int* pairs) {
    __shared__ float d[HRPB][HN];
    __shared__ float xr[HRPB][HC];
    const int t = threadIdx.x;
    const int b = blockIdx.x / (HN / HRPB);
    const int n0 = (blockIdx.x % (HN / HRPB)) * HRPB;
    const int r = t >> 6;
    const int lane = t & 63;
    xr[r][lane] = xT[(b * HC + lane) * HN + n0 + r];
    __syncthreads();
    float xs[HRPB];
    #pragma unroll
    for (int q = 0; q < HRPB; q++) xs[q] = xsq[b * HN + n0 + q];
    for (int m = t; m < HN; m += 256) {
        float dot0 = 0.f, dot1 = 0.f, dot2 = 0.f, dot3 = 0.f;
        #pragma unroll 8
        for (int c = 0; c < HC; c++) {
            float xv = xT[(b * HC + c) * HN + m];
            dot0 += xr[0][c] * xv;
            dot1 += xr[1][c] * xv;
            dot2 += xr[2][c] * xv;
            dot3 += xr[3][c] * xv;
        }
        float xsm = xsq[b * HN + m];
        d[0][m] = xs[0] + xsm - 2.f * dot0;
        d[1][m] = xs[1] + xsm - 2.f * dot1;
        d[2][m] = xs[2] + xsm - 2.f * dot2;
        d[3][m] = xs[3] + xsm - 2.f * dot3;
    }
    __syncthreads();
    const int p = n0 + r;
    unsigned int key[NSLOT];
    #pragma unroll
    for (int s = 0; s < NSLOT; s++) {
        float f = d[r][(s << 6) | lane];
        unsigned int ub = __float_as_uint(f);
        key[s] = ub ^ (((unsigned int)(((int)ub) >> 31)) | 0x80000000u);
    }
    const int gw = b * HN + p;
    hg14_select_emit(key, b, p, lane, max(Dv[gw], 1), offs[gw], indeg, pairs);
}

// -------- zero z (kNN part) and h2 — FALLBACK PATH ONLY -------------------
__global__ void hg14_zero(float* z, float* h2) {
    int i = blockIdx.x * 256 + threadIdx.x;      // over B*N*C
    int b = i / (HN * HC), rem = i % (HN * HC);
    z[b * HE * HC + rem] = 0.f;
    h2[i] = 0.f;
}

__device__ __forceinline__ int hg14_lo(int rc) { return max(0, (rc - 3) / 2); }
__device__ __forceinline__ int hg14_hi(int rc) { return min(HW - 1, rc / 2); }

// per-node right-scale factor s(n) = rsqrt(max(indeg + cover, 1))
__device__ __forceinline__ float hg25_s(const int* indeg, int b, int n) {
    int r = n / HL, c = n % HL;
    int cover = max(0, hg14_hi(r) - hg14_lo(r) + 1) * max(0, hg14_hi(c) - hg14_lo(c) + 1);
    int dvn = max(indeg[b * HN + n] + cover, 1);
    return rsqrtf((float)dvn);
}

// -------- fused edge kernel: kNN scatter + window means (+ scale fused) ---
__global__ __launch_bounds__(256) void hg25_edge(const unsigned int* pairs, const int* Dv,
                                                 const int* indeg, const float* y, float* z) {
    int wv = (blockIdx.x * 256 + threadIdx.x) >> 6;
    int lane = threadIdx.x & 63;
    if (wv < NPAIRS) {
        unsigned int pk = pairs[wv];
        int b = pk >> 24;
        if (b >= HB) return;                     // defensive (poison)
        int p = (pk >> 12) & 0xFFF, m = pk & 0xFFF;
        float invde = 1.f / (float)max(Dv[b * HN + p], 1);
        float sc = hg25_s(indeg, b, m);
        atomicAdd(&z[(b * HE + p) * HC + lane],
                  (y[(b * HN + m) * HC + lane] * sc) * invde);
    } else {
        int w2 = wv - NPAIRS;
        if (w2 >= HB * HE2) return;
        int b = w2 / HE2, w = w2 % HE2;
        int wr = w / HW, wc = w % HW;
        float acc = 0.f;
        #pragma unroll
        for (int i = 0; i < 5; i++)
            #pragma unroll
            for (int j = 0; j < 5; j++) {
                int n2 = (wr * 2 + i) * HL + wc * 2 + j;
                acc += y[(b * HN + n2) * HC + lane] * hg25_s(indeg, b, n2);
            }
        z[(b * HE + HN + w) * HC + lane] = acc * (1.f / 25.f);
    }
}

// -------- h2[m] += z[p] over the pair list (atomic) -----------------------
__global__ __launch_bounds__(256) void hg14_gscatter(const unsigned int* pairs,
                                                     const float* z, float* h2) {
    int idx = (blockIdx.x * 256 + threadIdx.x) >> 6;
    int lane = threadIdx.x & 63;
    if (idx >= NPAIRS) return;
    unsigned int pk = pairs[idx];
    int b = pk >> 24;
    if (b >= HB) return;                         // defensive (poison)
    int p = (pk >> 12) & 0xFFF, m = pk & 0xFFF;
    atomicAdd(&h2[(b * HN + m) * HC + lane], z[(b * HE + p) * HC + lane]);
}

// -------- add window contributions + final Dv^-1/2 scale ------------------
__global__ __launch_bounds__(256) void hg14_gfinish(const float* z, const int* indeg, float* h2) {
    int wave = (blockIdx.x * 256 + threadIdx.x) >> 6;  // one wave per (b, node)
    int lane = threadIdx.x & 63;
    int b = wave / HN, n = wave % HN;
    int g = b * HN + n;
    float acc = h2[g * HC + lane];
    int r = n / HL, c = n % HL;
    int rlo = hg14_lo(r), rhi = hg14_hi(r), clo = hg14_lo(c), chi = hg14_hi(c);
    for (int wr = rlo; wr <= rhi; wr++)
        for (int wc = clo; wc <= chi; wc++)
            acc += z[(b * HE + HN + wr * HW + wc) * HC + lane];
    int dvn = max(indeg[g] + max(0, rhi - rlo + 1) * max(0, chi - clo + 1), 1);
    h2[g * HC + lane] = acc * rsqrtf((float)dvn);
}

// -------- BN stats --------------------------------------------------------
__global__ __launch_bounds__(256) void hg14_bnstats(const float* h2, float* bnsum, float* bnss) {
    int t = threadIdx.x;
    int c = t & 63, rg = t >> 6;
    int row0 = blockIdx.x * 36;      // 256 blocks * 36 rows = 9216
    float s = 0.f, ss = 0.f;
    for (int r = rg; r < 36; r += 4) {
        float v = h2[(row0 + r) * HC + c];
        s += v; ss += v * v;
    }
    __shared__ float ls[256], lss[256];
    ls[t] = s; lss[t] = ss;
    __syncthreads();
    if (t < 64) {
        s  = ls[t]  + ls[t + 64]  + ls[t + 128]  + ls[t + 192];
        ss = lss[t] + lss[t + 64] + lss[t + 128] + lss[t + 192];
        atomicAdd(&bnsum[t], s);
        atomicAdd(&bnss[t], ss);
    }
}

// -------- BN + ReLU + residual --------------------------------------------
__global__ __launch_bounds__(256) void hg14_final(const float* h2, const float* x,
                                                  const float* gamma, const float* beta,
                                                  const float* bnsum, const float* bnss,
                                                  float* out) {
    int i = blockIdx.x * 256 + threadIdx.x;
    int c = i & 63;
    const float M = (float)(HB * HN);
    float mean = bnsum[c] / M;
    float var  = bnss[c] / M - mean * mean;
    float inv  = rsqrtf(var + 1e-5f);
    float h = gamma[c] * (h2[i] - mean) * inv + beta[c];
    out[i] = fmaxf(h, 0.f) + x[i];
}

extern "C" void kernel_launch(void* const* d_in, const int* in_sizes, int n_in,
                              void* d_out, int out_size, void* d_ws, size_t ws_size,
                              hipStream_t stream) {
    const float* x     = (const float*)d_in[0];
    const float* W     = (const float*)d_in[1];
    const float* bias  = (const float*)d_in[2];
    const float* gamma = (const float*)d_in[3];
    const float* beta  = (const float*)d_in[4];
    float* out = (float*)d_out;
    (void)in_sizes; (void)n_in;

    char* ws = (char*)d_ws;
    size_t off = 0;
    float*        xsq     = (float*)(ws + off);        off += (size_t)HB * HN * 4;
    float*        h1      = (float*)(ws + off);        off += (size_t)HB * HN * HC * 4;
    float*        h2      = (float*)(ws + off);        off += (size_t)HB * HN * HC * 4;
    int*          Dv      = (int*)(ws + off);          off += (size_t)HB * HN * 4;
    int*          indeg   = (int*)(ws + off);          off += (size_t)HB * HN * 4;
    int*          offs    = (int*)(ws + off);          off += (size_t)HB * HN * 4;
    unsigned int* pairs   = (unsigned int*)(ws + off); off += (size_t)NPAIRS * 4;
    float*        bnsum   = (float*)(ws + off);        off += 256;
    float*        bnss    = (float*)(ws + off);        off += 256;
    float*        xT      = (float*)(ws + off);        // z aliases xT (dead after kNN)
    float*        z       = (float*)(ws + off);
    off += (size_t)HB * HE * HC * 4;   // max(xT, z) = z
    size_t base_need = off;
    unsigned int* kcache  = (unsigned int*)(ws + off);
    size_t cache_need = off + (size_t)HB * HN * NSLOT * 64 * 4;   // +84.9 MB

    if (ws_size < base_need) {
        hg14_sentinel<<<(out_size + 255) / 256, 256, 0, stream>>>(out, out_size);
        return;
    }
    const int use_cache = (ws_size >= cache_need) ? 1 : 0;

    const int EDGE_WAVES = NPAIRS + HB * HE2;    // 103312, divisible by 4

    hg25_linear<<<HB * HN, 64, 0, stream>>>(x, W, bias, h1, xsq, xT,
                                            Dv, indeg, bnsum, bnss);
    hg24_knn_count<<<HB * (HN / HRPB), 256, 0, stream>>>(xT, xsq, Dv, kcache, use_cache);
    hg15_scan<<<1, 256, 0, stream>>>(Dv, offs);
    if (use_cache) {
        hg26_sel<<<HB * (HN / HRPB), 256, 0, stream>>>(kcache, Dv, offs, indeg,
                                                       pairs, z, h2);
    } else {
        hg14_knn_sel_full<<<HB * (HN / HRPB), 256, 0, stream>>>(xT, xsq, Dv, offs,
                                                                indeg, pairs);
        hg14_zero<<<(HB * HN * HC) / 256, 256, 0, stream>>>(z, h2);
    }
    hg25_edge<<<EDGE_WAVES / 4, 256, 0, stream>>>(pairs, Dv, indeg, h1, z);
    hg14_gscatter<<<(NPAIRS * 64) / 256, 256, 0, stream>>>(pairs, z, h2);
    hg14_gfinish<<<(HB * HN) / 4, 256, 0, stream>>>(z, indeg, h2);
    hg14_bnstats<<<256, 256, 0, stream>>>(h2, bnsum, bnss);
    hg14_final<<<(HB * HN * HC) / 256, 256, 0, stream>>>(h2, x, gamma, beta, bnsum, bnss, out);
}

// Round 15
// 326.529 us; speedup vs baseline: 1.2509x; 1.0629x over previous
//
#include <hip/hip_runtime.h>

// HGNN layer, v27 — fp32. v26 (347.1µs best) + sel fast path: count's pops
// extended 11 -> 20, storing sorted top-20 neighbor m's (csort, ushort,
// 368KB). sel rows with kk=Dv<=20 (~90-95%) emit directly from csort (20B
// vs 9KB of kcache keys); kk>20 rows keep the proven kcache+bisection path.
// Pair multiset identical (same (key,m)-lex top-kk; ties at threshold by
// ascending m in both paths); Dv = first 11 pops, bit-identical. Launch
// fusion lesson recorded: graph capture => dispatches ~free; only work
// reduction pays. B=4, N=2304, C=64.

#define HB    4
#define HN    2304
#define HC    64
#define HK    11             // K_NEIGS + 1
#define HL    48
#define HW    22             // windows per dim
#define HE2   484            // 22*22 local edges
#define HE    (HN + HE2)
#define HRPB  4              // rows per block == waves per block
#define NSLOT 36             // keys per lane (2304/64)
#define NCS   20             // sorted candidates stored per row (pops)
#define NPAIRS (HB * HK * HN)   // sum of Dv == 11*N per batch, exact

__global__ void hg14_sentinel(float* out, int n) {
    int i = blockIdx.x * 256 + threadIdx.x;
    if (i < n) out[i] = 12345.0f;
}

// -------- linear h1 = x W^T + b, xsq, f32 transpose, + init (fused) -------
__global__ __launch_bounds__(64) void hg25_linear(const float* x, const float* W,
                                                  const float* bias, float* h1,
                                                  float* xsq, float* xT,
                                                  int* Dv, int* indeg,
                                                  float* bnsum, float* bnss) {
    int row = blockIdx.x;            // 0..B*N-1
    int t = threadIdx.x;
    if (t == 0) { Dv[row] = 0; indeg[row] = 0; }
    if (row == 0) { bnsum[t] = 0.f; bnss[t] = 0.f; }
    __shared__ float xr[HC];
    float v = x[row * HC + t];
    xr[t] = v;
    __syncthreads();
    float sq = v * v;
    #pragma unroll
    for (int o = 32; o > 0; o >>= 1) sq += __shfl_xor(sq, o);
    if (t == 0) xsq[row] = sq;
    int b = row / HN, n = row % HN;
    xT[(b * HC + t) * HN + n] = v;
    float acc = bias[t];
    #pragma unroll 8
    for (int c = 0; c < HC; c++) acc += xr[c] * W[t * HC + c];
    h1[row * HC + t] = acc;
}

// ======== pop machinery (v12-proven) ======================================
__device__ __forceinline__ unsigned hg14_wave_min_u32(unsigned v) {
    #pragma unroll
    for (int o = 32; o > 0; o >>= 1) {
        unsigned ov = __shfl_xor(v, o);
        v = ov < v ? ov : v;
    }
    return v;
}

#define HG14_INS4(q0, q1, q2, q3, x)                                     \
    {                                                                    \
        unsigned long long x_ = (x), n_;                                 \
        n_ = q0 < x_ ? q0 : x_; x_ = q0 < x_ ? x_ : q0; q0 = n_;         \
        n_ = q1 < x_ ? q1 : x_; x_ = q1 < x_ ? x_ : q1; q1 = n_;         \
        n_ = q2 < x_ ? q2 : x_; x_ = q2 < x_ ? x_ : q2; q2 = n_;         \
        if (x_ < q3) q3 = x_;                                            \
    }

#define HG14_CE(u, v)                                                    \
    { unsigned long long t_ = u < v ? u : v; v = u < v ? v : u; u = t_; }

#define HG14_BUILD()                                                               \
    {                                                                              \
        unsigned long long a0 = CINF, a1 = CINF, a2 = CINF, a3 = CINF;             \
        unsigned long long b0 = CINF, b1 = CINF, b2 = CINF, b3 = CINF;             \
        _Pragma("unroll")                                                          \
        for (int s = 0; s < NSLOT / 2; s++) {                                      \
            unsigned long long pa = ((unsigned long long)key[s] << 12) |           \
                                    (unsigned)((s << 6) | lane);                   \
            unsigned long long pb = ((unsigned long long)key[s + 18] << 12) |      \
                                    (unsigned)(((s + 18) << 6) | lane);            \
            HG14_INS4(a0, a1, a2, a3, pa);                                         \
            HG14_INS4(b0, b1, b2, b3, pb);                                         \
        }                                                                          \
        c0 = a0 < b3 ? a0 : b3; c1 = a1 < b2 ? a1 : b2;                            \
        c2 = a2 < b1 ? a2 : b1; c3 = a3 < b0 ? a3 : b0;                            \
        HG14_CE(c0, c2); HG14_CE(c1, c3); HG14_CE(c0, c1); HG14_CE(c2, c3);        \
    }

#define HG14_EXTRACT(kk, EMIT)                                                     \
    {                                                                              \
        for (int j = 0; j < (kk); j++) {                                           \
            unsigned hk = (unsigned)(c0 >> 12);                                    \
            unsigned mk = hg14_wave_min_u32(hk);                                   \
            unsigned long long bal = __ballot(hk == mk);                           \
            bool iswin;                                                            \
            if (__popcll(bal) == 1) {                                              \
                iswin = (hk == mk);                                                \
            } else {                                                               \
                unsigned mc = (hk == mk) ? (unsigned)(c0 & 0xFFFu) : 0xFFFFFFFFu;  \
                unsigned mm = hg14_wave_min_u32(mc);                               \
                iswin = (mc == mm);                                                \
            }                                                                      \
            if (iswin) {                                                           \
                int bi = (int)(c0 & 0xFFFu);                                       \
                EMIT;                                                              \
                unsigned long long popped = c0;                                    \
                c0 = c1; c1 = c2; c2 = c3; c3 = CINF;                              \
                if (c0 == CINF) {                                                  \
                    _Pragma("unroll")                                              \
                    for (int s = 0; s < NSLOT; s++) {                              \
                        unsigned long long pk =                                    \
                            ((unsigned long long)key[s] << 12) |                   \
                            (unsigned)((s << 6) | lane);                           \
                        if (pk > popped) HG14_INS4(c0, c1, c2, c3, pk);            \
                    }                                                              \
                }                                                                  \
            }                                                                      \
        }                                                                          \
    }

// ======== bisection machinery (v13-proven): rare-row select path ==========
__device__ __forceinline__ void hg14_kth(const unsigned (&key)[NSLOT], int kk,
                                         unsigned& T, int& cntLess, int& take) {
    unsigned andv = 0xFFFFFFFFu, orv = 0u;
    #pragma unroll
    for (int s = 0; s < NSLOT; s++) { andv &= key[s]; orv |= key[s]; }
    #pragma unroll
    for (int o = 32; o > 0; o >>= 1) {
        andv &= (unsigned)__shfl_xor((int)andv, o);
        orv  |= (unsigned)__shfl_xor((int)orv, o);
    }
    unsigned diff = andv ^ orv;
    if (diff == 0u) { T = andv; cntLess = 0; take = kk; return; }
    int tstart = 31 - __builtin_clz(diff);
    unsigned lowmask = (tstart == 31) ? 0xFFFFFFFFu : ((1u << (tstart + 1)) - 1u);
    unsigned pref = andv & ~lowmask;
    int r = kk;
    for (int t = tstart; t >= 0; t--) {
        unsigned pt = pref >> t;
        int c = 0;
        #pragma unroll
        for (int s = 0; s < NSLOT; s++) c += ((key[s] >> t) == pt) ? 1 : 0;
        #pragma unroll
        for (int o = 32; o > 0; o >>= 1) c += __shfl_xor(c, o);
        if (r > c) { r -= c; pref |= (1u << t); }
    }
    T = pref; cntLess = kk - r; take = r;
}

__device__ __forceinline__ void hg14_scan64(int v, int lane, int& excl, int& total) {
    int inc = v;
    #pragma unroll
    for (int o = 1; o < 64; o <<= 1) {
        int u = __shfl_up(inc, o);
        if (lane >= o) inc += u;
    }
    excl = inc - v;
    total = __shfl(inc, 63);
}

// -------- kNN count v27: split-m float8 + 20 pops -> csort + kcache -------
#define HG24_R4(qq, ss, ww)                                              \
    qq.x += (ss) * ww.x; qq.y += (ss) * ww.y;                            \
    qq.z += (ss) * ww.z; qq.w += (ss) * ww.w;

#define HG24_ST4(row, qq, sv, mm)                                              \
    *reinterpret_cast<float4*>(&d[row][(mm)]) =                                \
        make_float4(xs[row] + sv.x - 2.f * qq.x, xs[row] + sv.y - 2.f * qq.y,  \
                    xs[row] + sv.z - 2.f * qq.z, xs[row] + sv.w - 2.f * qq.w);

__global__ __launch_bounds__(256) void hg27_knn_count(const float* xT, const float* xsq,
                                                      int* Dv, unsigned int* kcache,
                                                      unsigned short* csort,
                                                      int storekeys) {
    __shared__ float d[HRPB][HN];                // 36 KB
    __shared__ __align__(16) float xrt[HC][HRPB];// [c][row] -> b128 uniform reads
    const int t = threadIdx.x;
    const int b = blockIdx.x / (HN / HRPB);
    const int n0 = (blockIdx.x % (HN / HRPB)) * HRPB;
    const int r = t >> 6;
    const int lane = t & 63;
    xrt[lane][r] = xT[(b * HC + lane) * HN + n0 + r];
    __syncthreads();
    float xs[HRPB];
    #pragma unroll
    for (int q = 0; q < HRPB; q++) xs[q] = xsq[b * HN + n0 + q];

    {
        const int m = 4 * t;                     // A in [0,1024), B in [1024,2048)
        float4 q0a = {0.f,0.f,0.f,0.f}, q0b = {0.f,0.f,0.f,0.f};
        float4 q1a = {0.f,0.f,0.f,0.f}, q1b = {0.f,0.f,0.f,0.f};
        float4 q2a = {0.f,0.f,0.f,0.f}, q2b = {0.f,0.f,0.f,0.f};
        float4 q3a = {0.f,0.f,0.f,0.f}, q3b = {0.f,0.f,0.f,0.f};
        #pragma unroll 8
        for (int c = 0; c < HC; c++) {
            float4 xq = *reinterpret_cast<const float4*>(&xrt[c][0]);
            const float* bp = &xT[(b * HC + c) * HN + m];
            float4 ua = *reinterpret_cast<const float4*>(bp);
            float4 ub = *reinterpret_cast<const float4*>(bp + 1024);
            HG24_R4(q0a, xq.x, ua); HG24_R4(q0b, xq.x, ub);
            HG24_R4(q1a, xq.y, ua); HG24_R4(q1b, xq.y, ub);
            HG24_R4(q2a, xq.z, ua); HG24_R4(q2b, xq.z, ub);
            HG24_R4(q3a, xq.w, ua); HG24_R4(q3b, xq.w, ub);
        }
        float4 s0 = *reinterpret_cast<const float4*>(&xsq[b * HN + m]);
        float4 s1 = *reinterpret_cast<const float4*>(&xsq[b * HN + m + 1024]);
        HG24_ST4(0, q0a, s0, m); HG24_ST4(0, q0b, s1, m + 1024);
        HG24_ST4(1, q1a, s0, m); HG24_ST4(1, q1b, s1, m + 1024);
        HG24_ST4(2, q2a, s0, m); HG24_ST4(2, q2b, s1, m + 1024);
        HG24_ST4(3, q3a, s0, m); HG24_ST4(3, q3b, s1, m + 1024);
    }
    if (t < 64) {                                // tail: m = 2048 + 4t .. 2303
        const int m = 2048 + 4 * t;
        float4 q0 = {0.f,0.f,0.f,0.f}, q1 = {0.f,0.f,0.f,0.f};
        float4 q2 = {0.f,0.f,0.f,0.f}, q3 = {0.f,0.f,0.f,0.f};
        #pragma unroll 8
        for (int c = 0; c < HC; c++) {
            float4 xq = *reinterpret_cast<const float4*>(&xrt[c][0]);
            float4 ua = *reinterpret_cast<const float4*>(&xT[(b * HC + c) * HN + m]);
            HG24_R4(q0, xq.x, ua); HG24_R4(q1, xq.y, ua);
            HG24_R4(q2, xq.z, ua); HG24_R4(q3, xq.w, ua);
        }
        float4 s0 = *reinterpret_cast<const float4*>(&xsq[b * HN + m]);
        HG24_ST4(0, q0, s0, m); HG24_ST4(1, q1, s0, m);
        HG24_ST4(2, q2, s0, m); HG24_ST4(3, q3, s0, m);
    }
    __syncthreads();

    const int p = n0 + r;
    const unsigned long long CINF = ~0ull;
    unsigned int key[NSLOT];
    unsigned long long c0, c1, c2, c3;
    const int rowbase = (b * HN + p) * NSLOT;
    const size_t rowc = (size_t)(b * HN + p) * NCS;
    #pragma unroll
    for (int s = 0; s < NSLOT; s++) {
        float f = d[r][(s << 6) | lane];
        unsigned int ub = __float_as_uint(f);
        unsigned int k = ub ^ (((unsigned int)(((int)ub) >> 31)) | 0x80000000u);
        key[s] = k;
        if (storekeys) kcache[(rowbase + s) * 64 + lane] = k;
    }
    HG14_BUILD();
    // 20 pops in (key,m)-lex ascending order; first 11 define Dv (identical
    // to v14); every pop j stores candidate j for the sel fast path.
    HG14_EXTRACT(NCS,
        { if (j < HK) atomicAdd(&Dv[b * HN + bi], 1);
          csort[rowc + j] = (unsigned short)bi; });
}

// -------- exclusive scan of Dv (9216 = 256*36) into offs, wave-parallel ---
__global__ __launch_bounds__(256) void hg15_scan(const int* Dv, int* offs) {
    __shared__ int wsum[4];
    int t = threadIdx.x;
    int lane = t & 63, w = t >> 6;
    int base = t * 36;
    int s = 0;
    for (int i = 0; i < 36; i++) s += max(Dv[base + i], 1);
    int inc = s;
    #pragma unroll
    for (int o = 1; o < 64; o <<= 1) {
        int u = __shfl_up(inc, o);
        if (lane >= o) inc += u;
    }
    if (lane == 63) wsum[w] = inc;
    __syncthreads();
    int woff = 0;
    for (int i = 0; i < w; i++) woff += wsum[i];
    int acc = woff + inc - s;                    // exclusive prefix for this thread
    for (int i = 0; i < 36; i++) { offs[base + i] = acc; acc += max(Dv[base + i], 1); }
}

// -------- select body: threshold + parallel emission (v13-proven) ---------
__device__ __forceinline__ void hg14_select_emit(const unsigned (&key)[NSLOT],
                                                 int b, int p, int lane, int kk, int base,
                                                 int* indeg, unsigned int* pairs) {
    unsigned T; int cntLess, take;
    hg14_kth(key, kk, T, cntLess, take);
    int cl = 0;
    #pragma unroll
    for (int s = 0; s < NSLOT; s++) cl += (key[s] < T) ? 1 : 0;
    int off, tot;
    hg14_scan64(cl, lane, off, tot);
    int w = 0;
    #pragma unroll
    for (int s = 0; s < NSLOT; s++) {
        if (key[s] < T) {
            int m = (s << 6) | lane;
            atomicAdd(&indeg[b * HN + m], 1);
            pairs[base + off + w] =
                ((unsigned)b << 24) | ((unsigned)p << 12) | (unsigned)m;
            w++;
        }
    }
    int lastm = -1;
    for (int t2 = 0; t2 < take; t2++) {
        int mc = 0x7FFFFFFF;
        #pragma unroll
        for (int s = 0; s < NSLOT; s++) {
            int m = (s << 6) | lane;
            if (key[s] == T && m > lastm && m < mc) mc = m;
        }
        int mmin = mc;
        #pragma unroll
        for (int o = 32; o > 0; o >>= 1) {
            int ov = __shfl_xor(mmin, o);
            mmin = ov < mmin ? ov : mmin;
        }
        if (mc == mmin) {
            atomicAdd(&indeg[b * HN + mmin], 1);
            pairs[base + cntLess + t2] =
                ((unsigned)b << 24) | ((unsigned)p << 12) | (unsigned)mmin;
        }
        lastm = mmin;
    }
}

// -------- kNN select v27: csort fast path (kk<=20) + kcache fallback ------
__global__ __launch_bounds__(256) void hg27_sel(const unsigned short* csort,
                                                const unsigned int* kcache,
                                                const int* Dv, const int* offs,
                                                int* indeg, unsigned int* pairs,
                                                float* z, float* h2) {
    const int t = threadIdx.x;
    const int lane = t & 63;
    const int gw = blockIdx.x * HRPB + (t >> 6);   // global row 0..B*N-1
    const int b = gw / HN, p = gw % HN;
    // fused zeroing (was hg14_zero): h2 row + z kNN row. Safe: cached path
    // never reads xT (which z aliases); edge/gscatter run after this kernel.
    h2[gw * HC + lane] = 0.f;
    z[(b * HE + p) * HC + lane] = 0.f;
    const int kk = max(Dv[gw], 1);               // wave-uniform
    const int base = offs[gw];
    if (kk <= NCS) {
        // fast path: emit from count's sorted candidate list (same (key,m)-
        // lex top-kk multiset as the bisection path; order within row differs
        // but all consumers are order-independent)
        if (lane < kk) {
            int m = csort[(size_t)gw * NCS + lane];
            atomicAdd(&indeg[b * HN + m], 1);
            pairs[base + lane] =
                ((unsigned)b << 24) | ((unsigned)p << 12) | (unsigned)m;
        }
    } else {
        unsigned int key[NSLOT];
        const int rowbase = gw * NSLOT;
        #pragma unroll
        for (int s = 0; s < NSLOT; s++) key[s] = kcache[(rowbase + s) * 64 + lane];
        hg14_select_emit(key, b, p, lane, kk, base, indeg, pairs);
    }
}

// -------- kNN select, full recompute (fallback, no kcache ws) -------------
__global__ __launch_bounds__(256) void hg14_knn_sel_full(const float* xT, const float* xsq,
                                                         const int* Dv, const int* offs,
                                                         int* indeg, unsigned int* pairs) {
    __shared__ float d[HRPB][HN];
    __shared__ float xr[HRPB][HC];
    const int t = threadIdx.x;
    const int b = blockIdx.x / (HN / HRPB);
    const int n0 = (blockIdx.x % (HN / HRPB)) * HRPB;
    const int r = t >> 6;
    const int lane = t & 63;
    xr[r][lane] = xT[(b * HC + lane) * HN + n0 + r];
    __syncthreads();
    float xs[HRPB];
    #pragma unroll
    for (int q = 0; q < HRPB; q++) xs[q] = xsq[b * HN + n0 + q];
    for (int m = t; m < HN; m += 256) {
        float dot0 = 0.f, dot1 = 0.f, dot2 = 0.f, dot3 = 0.f;
        #pragma unroll 8
        for (int c = 0; c < HC; c++) {
            float xv = xT[(b * HC + c) * HN + m];
            dot0 += xr[0][c] * xv;
            dot1 += xr[1][c] * xv;
            dot2 += xr[2][c] * xv;
            dot3 += xr[3][c] * xv;
        }
        float xsm = xsq[b * HN + m];
        d[0][m] = xs[0] + xsm - 2.f * dot0;
        d[1][m] = xs[1] + xsm - 2.f * dot1;
        d[2][m] = xs[2] + xsm - 2.f * dot2;
        d[3][m] = xs[3] + xsm - 2.f * dot3;
    }
    __syncthreads();
    const int p = n0 + r;
    unsigned int key[NSLOT];
    #pragma unroll
    for (int s = 0; s < NSLOT; s++) {
        float f = d[r][(s << 6) | lane];
        unsigned int ub = __float_as_uint(f);
        key[s] = ub ^ (((unsigned int)(((int)ub) >> 31)) | 0x80000000u);
    }
    const int gw = b * HN + p;
    hg14_select_emit(key, b, p, lane, max(Dv[gw], 1), offs[gw], indeg, pairs);
}

// -------- zero z (kNN part) and h2 — FALLBACK PATH ONLY -------------------
__global__ void hg14_zero(float* z, float* h2) {
    int i = blockIdx.x * 256 + threadIdx.x;      // over B*N*C
    int b = i / (HN * HC), rem = i % (HN * HC);
    z[b * HE * HC + rem] = 0.f;
    h2[i] = 0.f;
}

__device__ __forceinline__ int hg14_lo(int rc) { return max(0, (rc - 3) / 2); }
__device__ __forceinline__ int hg14_hi(int rc) { return min(HW - 1, rc / 2); }

// per-node right-scale factor s(n) = rsqrt(max(indeg + cover, 1))
__device__ __forceinline__ float hg25_s(const int* indeg, int b, int n) {
    int r = n / HL, c = n % HL;
    int cover = max(0, hg14_hi(r) - hg14_lo(r) + 1) * max(0, hg14_hi(c) - hg14_lo(c) + 1);
    int dvn = max(indeg[b * HN + n] + cover, 1);
    return rsqrtf((float)dvn);
}

// -------- fused edge kernel: kNN scatter + window means (+ scale fused) ---
__global__ __launch_bounds__(256) void hg25_edge(const unsigned int* pairs, const int* Dv,
                                                 const int* indeg, const float* y, float* z) {
    int wv = (blockIdx.x * 256 + threadIdx.x) >> 6;
    int lane = threadIdx.x & 63;
    if (wv < NPAIRS) {
        unsigned int pk = pairs[wv];
        int b = pk >> 24;
        if (b >= HB) return;                     // defensive (poison)
        int p = (pk >> 12) & 0xFFF, m = pk & 0xFFF;
        float invde = 1.f / (float)max(Dv[b * HN + p], 1);
        float sc = hg25_s(indeg, b, m);
        atomicAdd(&z[(b * HE + p) * HC + lane],
                  (y[(b * HN + m) * HC + lane] * sc) * invde);
    } else {
        int w2 = wv - NPAIRS;
        if (w2 >= HB * HE2) return;
        int b = w2 / HE2, w = w2 % HE2;
        int wr = w / HW, wc = w % HW;
        float acc = 0.f;
        #pragma unroll
        for (int i = 0; i < 5; i++)
            #pragma unroll
            for (int j = 0; j < 5; j++) {
                int n2 = (wr * 2 + i) * HL + wc * 2 + j;
                acc += y[(b * HN + n2) * HC + lane] * hg25_s(indeg, b, n2);
            }
        z[(b * HE + HN + w) * HC + lane] = acc * (1.f / 25.f);
    }
}

// -------- h2[m] += z[p] over the pair list (atomic) -----------------------
__global__ __launch_bounds__(256) void hg14_gscatter(const unsigned int* pairs,
                                                     const float* z, float* h2) {
    int idx = (blockIdx.x * 256 + threadIdx.x) >> 6;
    int lane = threadIdx.x & 63;
    if (idx >= NPAIRS) return;
    unsigned int pk = pairs[idx];
    int b = pk >> 24;
    if (b >= HB) return;                         // defensive (poison)
    int p = (pk >> 12) & 0xFFF, m = pk & 0xFFF;
    atomicAdd(&h2[(b * HN + m) * HC + lane], z[(b * HE + p) * HC + lane]);
}

// -------- add window contributions + final Dv^-1/2 scale ------------------
__global__ __launch_bounds__(256) void hg14_gfinish(const float* z, const int* indeg, float* h2) {
    int wave = (blockIdx.x * 256 + threadIdx.x) >> 6;  // one wave per (b, node)
    int lane = threadIdx.x & 63;
    int b = wave / HN, n = wave % HN;
    int g = b * HN + n;
    float acc = h2[g * HC + lane];
    int r = n / HL, c = n % HL;
    int rlo = hg14_lo(r), rhi = hg14_hi(r), clo = hg14_lo(c), chi = hg14_hi(c);
    for (int wr = rlo; wr <= rhi; wr++)
        for (int wc = clo; wc <= chi; wc++)
            acc += z[(b * HE + HN + wr * HW + wc) * HC + lane];
    int dvn = max(indeg[g] + max(0, rhi - rlo + 1) * max(0, chi - clo + 1), 1);
    h2[g * HC + lane] = acc * rsqrtf((float)dvn);
}

// -------- BN stats --------------------------------------------------------
__global__ __launch_bounds__(256) void hg14_bnstats(const float* h2, float* bnsum, float* bnss) {
    int t = threadIdx.x;
    int c = t & 63, rg = t >> 6;
    int row0 = blockIdx.x * 36;      // 256 blocks * 36 rows = 9216
    float s = 0.f, ss = 0.f;
    for (int r = rg; r < 36; r += 4) {
        float v = h2[(row0 + r) * HC + c];
        s += v; ss += v * v;
    }
    __shared__ float ls[256], lss[256];
    ls[t] = s; lss[t] = ss;
    __syncthreads();
    if (t < 64) {
        s  = ls[t]  + ls[t + 64]  + ls[t + 128]  + ls[t + 192];
        ss = lss[t] + lss[t + 64] + lss[t + 128] + lss[t + 192];
        atomicAdd(&bnsum[t], s);
        atomicAdd(&bnss[t], ss);
    }
}

// -------- BN + ReLU + residual --------------------------------------------
__global__ __launch_bounds__(256) void hg14_final(const float* h2, const float* x,
                                                  const float* gamma, const float* beta,
                                                  const float* bnsum, const float* bnss,
                                                  float* out) {
    int i = blockIdx.x * 256 + threadIdx.x;
    int c = i & 63;
    const float M = (float)(HB * HN);
    float mean = bnsum[c] / M;
    float var  = bnss[c] / M - mean * mean;
    float inv  = rsqrtf(var + 1e-5f);
    float h = gamma[c] * (h2[i] - mean) * inv + beta[c];
    out[i] = fmaxf(h, 0.f) + x[i];
}

extern "C" void kernel_launch(void* const* d_in, const int* in_sizes, int n_in,
                              void* d_out, int out_size, void* d_ws, size_t ws_size,
                              hipStream_t stream) {
    const float* x     = (const float*)d_in[0];
    const float* W     = (const float*)d_in[1];
    const float* bias  = (const float*)d_in[2];
    const float* gamma = (const float*)d_in[3];
    const float* beta  = (const float*)d_in[4];
    float* out = (float*)d_out;
    (void)in_sizes; (void)n_in;

    char* ws = (char*)d_ws;
    size_t off = 0;
    float*          xsq     = (float*)(ws + off);          off += (size_t)HB * HN * 4;
    float*          h1      = (float*)(ws + off);          off += (size_t)HB * HN * HC * 4;
    float*          h2      = (float*)(ws + off);          off += (size_t)HB * HN * HC * 4;
    int*            Dv      = (int*)(ws + off);            off += (size_t)HB * HN * 4;
    int*            indeg   = (int*)(ws + off);            off += (size_t)HB * HN * 4;
    int*            offs    = (int*)(ws + off);            off += (size_t)HB * HN * 4;
    unsigned int*   pairs   = (unsigned int*)(ws + off);   off += (size_t)NPAIRS * 4;
    unsigned short* csort   = (unsigned short*)(ws + off); off += (size_t)HB * HN * NCS * 2;
    float*          bnsum   = (float*)(ws + off);          off += 256;
    float*          bnss    = (float*)(ws + off);          off += 256;
    float*          xT      = (float*)(ws + off);          // z aliases xT (dead after kNN)
    float*          z       = (float*)(ws + off);
    off += (size_t)HB * HE * HC * 4;   // max(xT, z) = z
    size_t base_need = off;
    unsigned int*   kcache  = (unsigned int*)(ws + off);
    size_t cache_need = off + (size_t)HB * HN * NSLOT * 64 * 4;   // +84.9 MB

    if (ws_size < base_need) {
        hg14_sentinel<<<(out_size + 255) / 256, 256, 0, stream>>>(out, out_size);
        return;
    }
    const int use_cache = (ws_size >= cache_need) ? 1 : 0;

    const int EDGE_WAVES = NPAIRS + HB * HE2;    // 103312, divisible by 4

    hg25_linear<<<HB * HN, 64, 0, stream>>>(x, W, bias, h1, xsq, xT,
                                            Dv, indeg, bnsum, bnss);
    hg27_knn_count<<<HB * (HN / HRPB), 256, 0, stream>>>(xT, xsq, Dv, kcache,
                                                         csort, use_cache);
    hg15_scan<<<1, 256, 0, stream>>>(Dv, offs);
    if (use_cache) {
        hg27_sel<<<HB * (HN / HRPB), 256, 0, stream>>>(csort, kcache, Dv, offs,
                                                       indeg, pairs, z, h2);
    } else {
        hg14_knn_sel_full<<<HB * (HN / HRPB), 256, 0, stream>>>(xT, xsq, Dv, offs,
                                                                indeg, pairs);
        hg14_zero<<<(HB * HN * HC) / 256, 256, 0, stream>>>(z, h2);
    }
    hg25_edge<<<EDGE_WAVES / 4, 256, 0, stream>>>(pairs, Dv, indeg, h1, z);
    hg14_gscatter<<<(NPAIRS * 64) / 256, 256, 0, stream>>>(pairs, z, h2);
    hg14_gfinish<<<(HB * HN) / 4, 256, 0, stream>>>(z, indeg, h2);
    hg14_bnstats<<<256, 256, 0, stream>>>(h2, bnsum, bnss);
    hg14_final<<<(HB * HN * HC) / 256, 256, 0, stream>>>(h2, x, gamma, beta, bnsum, bnss, out);
}